// Round 8
// baseline (256.887 us; speedup 1.0000x reference)
//
#include <hip/hip_runtime.h>

#define BSZ 8
#define LSEQ 8192
#define DDIM 256
#define CHUNK 16
#define WARM 32
#define STEPS (CHUNK + WARM)   // 48
#define CPB 16                 // chains per block

typedef float f32x4 __attribute__((ext_vector_type(4)));
typedef _Float16 h8 __attribute__((ext_vector_type(8)));

// U layout: PLAIN row-major [row][col] fp16 (swizzle dropped: scan waves own
// 16 cols, so per-lane U access is a scalar 2B load; 16-lane group = 32B segment).
//
// Register policy lesson (R4-R6): the allocator refuses >~100 VGPRs here no
// matter what attributes we set; so both kernels are restructured to NEED <100:
//   scan: 16 waves x 16 cols -> bf[8]+cf[8] = 64 frag VGPRs (was 128)
//   gemm_u: wave owns 16 cols -> bf[8] = 32 frag VGPRs; af rebuilt from LDS
// R7 crashed on a staging-loop bound bug (64 iters for a 64-row tile -> rows
// up to 255, LDS OOB). Fixed here: 16 iters. No other change.

// ---------------- U = x @ B^T (+ folded matrix conversions) ----------------
// 1024 blocks x 64 rows, 256 threads (4 waves), 2 blocks/CU.
// x staged fp32 -> padded LDS [64][276] (276%32=20 -> near-conflict-free).
// B read fp32 directly (L2-resident), converted in-register: no Bh pass.
// First 256 blocks also emit AhT/Ch fp16 + zero page (scan runs after us).
__global__ __launch_bounds__(256) void k_gemm_u(
    const float* __restrict__ x, const float* __restrict__ A,
    const float* __restrict__ B, const float* __restrict__ C,
    _Float16* __restrict__ U, _Float16* __restrict__ AhT,
    _Float16* __restrict__ Ch, _Float16* __restrict__ Zph) {
  __shared__ __align__(16) float xs[64][276];
  const int tid = threadIdx.x, wv = tid >> 6, lane = tid & 63;
  const int l15 = lane & 15, q = lane >> 4;

  if (blockIdx.x < 256) {  // side duty: conversions for the scan
    const int r = blockIdx.x;
    AhT[tid * 256 + r] = (_Float16)A[r * 256 + tid];
    Ch[r * 256 + tid] = (_Float16)C[r * 256 + tid];
    if (r == 0) { Zph[tid] = (_Float16)0.f; Zph[tid + 256] = (_Float16)0.f; }
  }

  const size_t rowbase = (size_t)blockIdx.x * 64;
#pragma unroll
  for (int i = 0; i < 16; ++i) {  // 4096 float4 = 64 rows x 64 float4/row
    const int f4 = i * 256 + tid;
    const int row = f4 >> 6, c4 = f4 & 63;  // each wave: one full row per iter
    float4 v = *(const float4*)(x + (rowbase + row) * 256 + c4 * 4);
    *(float4*)&xs[row][c4 * 4] = v;
  }
  __syncthreads();

#pragma unroll 1
  for (int cg = 0; cg < 4; ++cg) {
    const int n = cg * 64 + wv * 16 + l15;  // this wave's output col
    h8 bf[8];  // B^T fragment: Bt[k][n] = B[n][k] -> 8 consecutive fp32
#pragma unroll
    for (int kb = 0; kb < 8; ++kb) {
      const float* bp = B + (size_t)n * 256 + kb * 32 + q * 8;
      float4 b0 = *(const float4*)bp, b1 = *(const float4*)(bp + 4);
      h8 f;
      f[0] = (_Float16)b0.x; f[1] = (_Float16)b0.y; f[2] = (_Float16)b0.z; f[3] = (_Float16)b0.w;
      f[4] = (_Float16)b1.x; f[5] = (_Float16)b1.y; f[6] = (_Float16)b1.z; f[7] = (_Float16)b1.w;
      bf[kb] = f;
    }
#pragma unroll 1
    for (int rt = 0; rt < 4; ++rt) {
      f32x4 acc = {};
#pragma unroll
      for (int kb = 0; kb < 8; ++kb) {
        const float* xp = &xs[rt * 16 + l15][kb * 32 + q * 8];
        float4 x0 = *(const float4*)xp, x1 = *(const float4*)(xp + 4);
        h8 af;
        af[0] = (_Float16)x0.x; af[1] = (_Float16)x0.y; af[2] = (_Float16)x0.z; af[3] = (_Float16)x0.w;
        af[4] = (_Float16)x1.x; af[5] = (_Float16)x1.y; af[6] = (_Float16)x1.z; af[7] = (_Float16)x1.w;
        acc = __builtin_amdgcn_mfma_f32_16x16x32_f16(af, bf[kb], acc, 0, 0, 0);
      }
      const size_t grow = rowbase + rt * 16 + q * 4;
#pragma unroll
      for (int r = 0; r < 4; ++r)
        U[(grow + r) * 256 + n] = (_Float16)acc[r];
    }
  }
}

// ---------------- fused MFMA scan + out-projection ----------------
// 256 blocks / CHUNK=16 / 1 block/CU (proven memory pattern). NOW 16 waves
// (1024 threads), each owning 16 output cols: fragment need = 64 VGPRs/wave
// (under the allocator's ~100 clamp), 4 waves/SIMD of latency overlap.
// Sync structure unchanged: st dbuf, lgkmcnt-only barrier, U zero-page clamp.
__global__ __launch_bounds__(1024) void k_scan(const _Float16* __restrict__ U,
                                               const _Float16* __restrict__ AhT,
                                               const _Float16* __restrict__ Ch,
                                               const _Float16* __restrict__ Zph,
                                               float* __restrict__ O) {
  __shared__ __align__(16) _Float16 st[2][CPB][264];  // state dbuf, proven layout
  const int tid = threadIdx.x, wv = tid >> 6, lane = tid & 63;  // wv 0..15
  const int l15 = lane & 15, q = lane >> 4;
  const int nc = wv * 16 + l15;  // this lane's output col
  const int b = blockIdx.x >> 5;
  const int c0 = (blockIdx.x & 31) * CPB;
  const size_t bbase = (size_t)b * LSEQ;

  h8 bf[8], cf[8];
#pragma unroll
  for (int kb = 0; kb < 8; ++kb) {
    const size_t mo = (size_t)nc * 256 + kb * 32 + q * 8;
    bf[kb] = *(const h8*)(AhT + mo);
    cf[kb] = *(const h8*)(Ch + mo);
  }

  for (int i = tid; i < CPB * 264; i += 1024) ((_Float16*)st[0])[i] = (_Float16)0.f;

  // per-lane U value (2B) for chain q*4+r at local time t (clamped to zero page)
  auto uload = [&](int t, int r) -> _Float16 {
    const int lr = (c0 + q * 4 + r) * CHUNK + t;
    const _Float16* p = (lr < 0 || lr >= LSEQ) ? (Zph + l15)
                                               : (U + (bbase + (size_t)lr) * 256 + nc);
    return *p;
  };

  float* op[4];
#pragma unroll
  for (int r = 0; r < 4; ++r)
    op[r] = O + (bbase + (size_t)(c0 + q * 4 + r) * CHUNK) * 256 + nc;

  _Float16 up0 = uload(-WARM, 0), up1 = uload(-WARM, 1);
  _Float16 up2 = uload(-WARM, 2), up3 = uload(-WARM, 3);
  __syncthreads();  // one full drain: zero-init + frag loads

  int cb = 0;
#pragma unroll 1
  for (int g = 0; g <= STEPS; ++g) {
    const int t = g - WARM;  // computes S_t (g<STEPS); emits O_{t-1} (t>=1)
    // prefetch next step's U values (overlap this step's MFMA; never drained)
    _Float16 un0 = uload(t + 1, 0), un1 = uload(t + 1, 1);
    _Float16 un2 = uload(t + 1, 2), un3 = uload(t + 1, 3);
    if (g < STEPS) {
      f32x4 acc;
      acc[0] = (float)up0; acc[1] = (float)up1; acc[2] = (float)up2; acc[3] = (float)up3;
      if (t >= 1) {
        f32x4 acc2 = {};
#pragma unroll
        for (int kb = 0; kb < 8; ++kb) {
          h8 af = *(const h8*)&st[cb][l15][kb * 32 + q * 8];
          acc = __builtin_amdgcn_mfma_f32_16x16x32_f16(af, bf[kb], acc, 0, 0, 0);
          acc2 = __builtin_amdgcn_mfma_f32_16x16x32_f16(af, cf[kb], acc2, 0, 0, 0);
        }
#pragma unroll
        for (int r = 0; r < 4; ++r)
          st[cb ^ 1][q * 4 + r][nc] = (_Float16)acc[r];
#pragma unroll
        for (int r = 0; r < 4; ++r) {
          op[r][0] = acc2[r];
          op[r] += 256;
        }
      } else {
#pragma unroll
        for (int kb = 0; kb < 8; ++kb) {
          h8 af = *(const h8*)&st[cb][l15][kb * 32 + q * 8];
          acc = __builtin_amdgcn_mfma_f32_16x16x32_f16(af, bf[kb], acc, 0, 0, 0);
        }
#pragma unroll
        for (int r = 0; r < 4; ++r)
          st[cb ^ 1][q * 4 + r][nc] = (_Float16)acc[r];
      }
    } else {  // g == STEPS: final O_{CHUNK-1} only
      f32x4 acc2 = {};
#pragma unroll
      for (int kb = 0; kb < 8; ++kb) {
        h8 af = *(const h8*)&st[cb][l15][kb * 32 + q * 8];
        acc2 = __builtin_amdgcn_mfma_f32_16x16x32_f16(af, cf[kb], acc2, 0, 0, 0);
      }
#pragma unroll
      for (int r = 0; r < 4; ++r)
        op[r][0] = acc2[r];
    }
    // cross-wave hazard is LDS-only (st dbuf): wait LDS, barrier — NO vmem drain
    asm volatile("s_waitcnt lgkmcnt(0)" ::: "memory");
    __builtin_amdgcn_s_barrier();
    asm volatile("" ::: "memory");
    up0 = un0; up1 = un1; up2 = un2; up3 = un3;
    cb ^= 1;
  }
}

extern "C" void kernel_launch(void* const* d_in, const int* in_sizes, int n_in,
                              void* d_out, int out_size, void* d_ws, size_t ws_size,
                              hipStream_t stream) {
  const float* x = (const float*)d_in[0];
  const float* A = (const float*)d_in[1];
  const float* B = (const float*)d_in[2];
  const float* C = (const float*)d_in[3];

  char* ws = (char*)d_ws;
  _Float16* U = (_Float16*)ws;                            // 33.5 MB (row-major)
  _Float16* AhT = (_Float16*)(ws + 33554432);             // 128 KB
  _Float16* Ch = (_Float16*)(ws + 33554432 + 131072);     // 128 KB
  _Float16* Zph = (_Float16*)(ws + 33554432 + 262144);    // 1 KB zeros
  float* out = (float*)d_out;

  hipLaunchKernelGGL(k_gemm_u, dim3(1024), dim3(256), 0, stream, x, A, B, C, U, AhT,
                     Ch, Zph);
  hipLaunchKernelGGL(k_scan, dim3(256), dim3(1024), 0, stream, U, AhT, Ch, Zph, out);
}

// Round 9
// 211.458 us; speedup vs baseline: 1.2148x; 1.2148x over previous
//
#include <hip/hip_runtime.h>

#define BSZ 8
#define LSEQ 8192
#define DDIM 256
#define CHUNK 16
#define WARM 32
#define STEPS (CHUNK + WARM)   // 48
#define CPB 16                 // chains per block

typedef float f32x4 __attribute__((ext_vector_type(4)));
typedef _Float16 h8 __attribute__((ext_vector_type(8)));
typedef _Float16 h4 __attribute__((ext_vector_type(4)));
typedef _Float16 h2 __attribute__((ext_vector_type(2)));

// U layout (R4-proven): row-major rows, cols swizzled within each 64-block:
//   U[row*256 + g64*64 + l15*4 + ct] == logical U[row][g64*64 + ct*16 + l15]
// scan lane reads its 2 ct-values (pair hf) as ONE 4B load; gemm_u writes h2.
//
// Lessons enforced here:
//  R8: LDS af traffic = nwaves * 8KB/step -> 8 waves x 32 cols is the sweet
//      spot (64KB/step); 16 waves doubled it and lost 2x. Reverted to R4 scan.
//  R4-R6: allocator clamps ~88-100 VGPR; shrink live sets to FIT instead of
//      fighting it: gemm_u processes ct-PAIRS (bf[2][8]=64 regs, short scope).
//  New: 2-step-ahead U prefetch (triple buffer) + warm/main loop split.

// ---------------- U = x @ B^T (+ folded matrix conversions) ----------------
// 512 blocks x 128 rows, 256 threads (4 waves x 32 rows), 2 blocks/CU.
// x staged once to LDS as fp16; B converted fp32->fp16 in-register (no Bh
// pass, no cvt kernel). First 256 blocks also emit AhT/Ch/Zph for the scan.
__global__ __launch_bounds__(256) void k_gemm_u(
    const float* __restrict__ x, const float* __restrict__ A,
    const float* __restrict__ B, const float* __restrict__ C,
    _Float16* __restrict__ U, _Float16* __restrict__ AhT,
    _Float16* __restrict__ Ch, _Float16* __restrict__ Zph) {
  __shared__ __align__(16) _Float16 xh[128][264];
  const int tid = threadIdx.x, wv = tid >> 6, lane = tid & 63;
  const int l15 = lane & 15, q = lane >> 4;

  if (blockIdx.x < 256) {  // side duty: operand conversions for the scan
    const int r = blockIdx.x;
    AhT[tid * 256 + r] = (_Float16)A[r * 256 + tid];   // AhT[n][k] = A[k][n]
    Ch[r * 256 + tid] = (_Float16)C[r * 256 + tid];    // Ch[n][k]  = C[n][k]
    if (r == 0) { Zph[tid] = (_Float16)0.f; Zph[tid + 256] = (_Float16)0.f; }
  }

  const size_t rowbase = (size_t)blockIdx.x * 128;
#pragma unroll
  for (int i = 0; i < 32; ++i) {  // 8192 float4 = 128 rows x 64 float4/row
    const int f4 = i * 256 + tid;
    const int row = f4 >> 6, c4 = f4 & 63;
    float4 v = *(const float4*)(x + (rowbase + row) * 256 + c4 * 4);
    h4 h;
    h[0] = (_Float16)v.x; h[1] = (_Float16)v.y; h[2] = (_Float16)v.z; h[3] = (_Float16)v.w;
    *(h4*)&xh[row][c4 * 4] = h;
  }
  __syncthreads();

#pragma unroll 1
  for (int cbk = 0; cbk < 4; ++cbk) {
#pragma unroll 1
    for (int ch = 0; ch < 2; ++ch) {  // ct-pair: live set = 64 frag VGPRs
      h8 bf[2][8];
#pragma unroll
      for (int ctl = 0; ctl < 2; ++ctl)
#pragma unroll
        for (int kb = 0; kb < 8; ++kb) {
          const float* bp =
              B + (size_t)(cbk * 64 + (2 * ch + ctl) * 16 + l15) * 256 + kb * 32 + q * 8;
          float4 b0 = *(const float4*)bp, b1 = *(const float4*)(bp + 4);
          h8 f;
          f[0] = (_Float16)b0.x; f[1] = (_Float16)b0.y; f[2] = (_Float16)b0.z; f[3] = (_Float16)b0.w;
          f[4] = (_Float16)b1.x; f[5] = (_Float16)b1.y; f[6] = (_Float16)b1.z; f[7] = (_Float16)b1.w;
          bf[ctl][kb] = f;
        }
#pragma unroll
      for (int rt = 0; rt < 2; ++rt) {
        const int rloc = wv * 32 + rt * 16;
        f32x4 acc[2] = {};
#pragma unroll
        for (int kb = 0; kb < 8; ++kb) {
          h8 af = *(const h8*)&xh[rloc + l15][kb * 32 + q * 8];
#pragma unroll
          for (int ctl = 0; ctl < 2; ++ctl)
            acc[ctl] = __builtin_amdgcn_mfma_f32_16x16x32_f16(af, bf[ctl][kb], acc[ctl], 0, 0, 0);
        }
        const size_t grow = rowbase + rloc + q * 4;
#pragma unroll
        for (int r = 0; r < 4; ++r) {
          h2 hv;
          hv[0] = (_Float16)acc[0][r]; hv[1] = (_Float16)acc[1][r];
          *(h2*)(U + (grow + r) * 256 + cbk * 64 + l15 * 4 + 2 * ch) = hv;  // swizzle
        }
      }
    }
  }
}

// ---------------- fused MFMA scan + out-projection (R4 base) ----------------
// 256 blocks / CHUNK=16 / 1 block/CU; 8 waves x 32 cols (64KB LDS af/step —
// the measured sweet spot). New vs R4: U prefetched TWO steps ahead (triple
// buffer, hides ~900cyc HBM latency) and warm/main loop split (zero-page
// select off the main path; single min() clamp covers the t+2 overrun).
__global__ __launch_bounds__(512) void k_scan(const _Float16* __restrict__ U,
                                              const _Float16* __restrict__ AhT,
                                              const _Float16* __restrict__ Ch,
                                              const _Float16* __restrict__ Zph,
                                              float* __restrict__ O) {
  __shared__ __align__(16) _Float16 st[2][CPB][264];  // state dbuf, proven layout
  const int tid = threadIdx.x, wv = tid >> 6, lane = tid & 63;
  const int l15 = lane & 15, q = lane >> 4;
  const int g64 = wv >> 1, hf = wv & 1;   // wave owns cols g64*64 + (2hf+ctl)*16 + l15
  const int b = blockIdx.x >> 5;
  const int c0 = (blockIdx.x & 31) * CPB;
  const size_t bbase = (size_t)b * LSEQ;

  h8 bf[2][8], cf[2][8];
#pragma unroll
  for (int ctl = 0; ctl < 2; ++ctl)
#pragma unroll
    for (int kb = 0; kb < 8; ++kb) {
      const size_t mo = (size_t)(g64 * 64 + (2 * hf + ctl) * 16 + l15) * 256 + kb * 32 + q * 8;
      bf[ctl][kb] = *(const h8*)(AhT + mo);
      cf[ctl][kb] = *(const h8*)(Ch + mo);
    }

  for (int i = tid; i < CPB * 264; i += 512) ((_Float16*)st[0])[i] = (_Float16)0.f;

  const int coff = g64 * 64 + l15 * 4 + 2 * hf;  // this lane's U/swizzle offset
  // warm-phase load: t may be negative -> zero page
  auto uload_w = [&](int t, int r) -> h2 {
    const int lr = (c0 + q * 4 + r) * CHUNK + t;
    const _Float16* p = (lr < 0) ? (Zph + l15 * 4 + 2 * hf)
                                 : (U + (bbase + (size_t)lr) * 256 + coff);
    return *(const h2*)p;
  };
  // main-phase load: t>=0 always; clamp the t+2 overrun at the batch tail
  auto uload_m = [&](int t, int r) -> h2 {
    int lr = (c0 + q * 4 + r) * CHUNK + t;
    lr = lr > (LSEQ - 1) ? (LSEQ - 1) : lr;
    return *(const h2*)(U + (bbase + (size_t)lr) * 256 + coff);
  };

  float* op[4];
#pragma unroll
  for (int r = 0; r < 4; ++r)
    op[r] = O + (bbase + (size_t)(c0 + q * 4 + r) * CHUNK) * 256 + g64 * 64 + 2 * hf * 16 + l15;

  h2 up0 = uload_w(-WARM, 0), up1 = uload_w(-WARM, 1);
  h2 up2 = uload_w(-WARM, 2), up3 = uload_w(-WARM, 3);
  h2 un0 = uload_w(-WARM + 1, 0), un1 = uload_w(-WARM + 1, 1);
  h2 un2 = uload_w(-WARM + 1, 2), un3 = uload_w(-WARM + 1, 3);
  __syncthreads();  // one full drain: zero-init + frag loads

  int cb = 0;
  // ---- warm loop: g = 0..WARM-1 (t < 0): S-update only ----
#pragma unroll 1
  for (int g = 0; g < WARM; ++g) {
    const int t = g - WARM;
    h2 uf0 = uload_w(t + 2, 0), uf1 = uload_w(t + 2, 1);
    h2 uf2 = uload_w(t + 2, 2), uf3 = uload_w(t + 2, 3);
    f32x4 acc[2];
#pragma unroll
    for (int ctl = 0; ctl < 2; ++ctl) {
      acc[ctl][0] = (float)up0[ctl]; acc[ctl][1] = (float)up1[ctl];
      acc[ctl][2] = (float)up2[ctl]; acc[ctl][3] = (float)up3[ctl];
    }
#pragma unroll
    for (int kb = 0; kb < 8; ++kb) {
      h8 af = *(const h8*)&st[cb][l15][kb * 32 + q * 8];
#pragma unroll
      for (int ctl = 0; ctl < 2; ++ctl)
        acc[ctl] = __builtin_amdgcn_mfma_f32_16x16x32_f16(af, bf[ctl][kb], acc[ctl], 0, 0, 0);
    }
#pragma unroll
    for (int ctl = 0; ctl < 2; ++ctl)
#pragma unroll
      for (int r = 0; r < 4; ++r)
        st[cb ^ 1][q * 4 + r][g64 * 64 + (2 * hf + ctl) * 16 + l15] = (_Float16)acc[ctl][r];
    asm volatile("s_waitcnt lgkmcnt(0)" ::: "memory");
    __builtin_amdgcn_s_barrier();
    asm volatile("" ::: "memory");
    up0 = un0; up1 = un1; up2 = un2; up3 = un3;
    un0 = uf0; un1 = uf1; un2 = uf2; un3 = uf3;
    cb ^= 1;
  }
  // ---- main loop: g = WARM..STEPS (t = 0..CHUNK): S-update + O ----
#pragma unroll 1
  for (int g = WARM; g <= STEPS; ++g) {
    const int t = g - WARM;  // computes S_t (g<STEPS); emits O_{t-1} (t>=1)
    h2 uf0 = uload_m(t + 2, 0), uf1 = uload_m(t + 2, 1);
    h2 uf2 = uload_m(t + 2, 2), uf3 = uload_m(t + 2, 3);
    if (g < STEPS) {
      f32x4 acc[2];
#pragma unroll
      for (int ctl = 0; ctl < 2; ++ctl) {
        acc[ctl][0] = (float)up0[ctl]; acc[ctl][1] = (float)up1[ctl];
        acc[ctl][2] = (float)up2[ctl]; acc[ctl][3] = (float)up3[ctl];
      }
      if (t >= 1) {
        f32x4 acc2[2] = {};
#pragma unroll
        for (int kb = 0; kb < 8; ++kb) {
          h8 af = *(const h8*)&st[cb][l15][kb * 32 + q * 8];
#pragma unroll
          for (int ctl = 0; ctl < 2; ++ctl)
            acc[ctl] = __builtin_amdgcn_mfma_f32_16x16x32_f16(af, bf[ctl][kb], acc[ctl], 0, 0, 0);
#pragma unroll
          for (int ctl = 0; ctl < 2; ++ctl)
            acc2[ctl] = __builtin_amdgcn_mfma_f32_16x16x32_f16(af, cf[ctl][kb], acc2[ctl], 0, 0, 0);
        }
#pragma unroll
        for (int ctl = 0; ctl < 2; ++ctl)
#pragma unroll
          for (int r = 0; r < 4; ++r)
            st[cb ^ 1][q * 4 + r][g64 * 64 + (2 * hf + ctl) * 16 + l15] = (_Float16)acc[ctl][r];
#pragma unroll
        for (int r = 0; r < 4; ++r) {
          op[r][0] = acc2[0][r];
          op[r][16] = acc2[1][r];
          op[r] += 256;
        }
      } else {  // t == 0
#pragma unroll
        for (int kb = 0; kb < 8; ++kb) {
          h8 af = *(const h8*)&st[cb][l15][kb * 32 + q * 8];
#pragma unroll
          for (int ctl = 0; ctl < 2; ++ctl)
            acc[ctl] = __builtin_amdgcn_mfma_f32_16x16x32_f16(af, bf[ctl][kb], acc[ctl], 0, 0, 0);
        }
#pragma unroll
        for (int ctl = 0; ctl < 2; ++ctl)
#pragma unroll
          for (int r = 0; r < 4; ++r)
            st[cb ^ 1][q * 4 + r][g64 * 64 + (2 * hf + ctl) * 16 + l15] = (_Float16)acc[ctl][r];
      }
    } else {  // g == STEPS: final O_{CHUNK-1} only
      f32x4 acc2[2] = {};
#pragma unroll
      for (int kb = 0; kb < 8; ++kb) {
        h8 af = *(const h8*)&st[cb][l15][kb * 32 + q * 8];
#pragma unroll
        for (int ctl = 0; ctl < 2; ++ctl)
          acc2[ctl] = __builtin_amdgcn_mfma_f32_16x16x32_f16(af, cf[ctl][kb], acc2[ctl], 0, 0, 0);
      }
#pragma unroll
      for (int r = 0; r < 4; ++r) {
        op[r][0] = acc2[0][r];
        op[r][16] = acc2[1][r];
      }
    }
    // cross-wave hazard is LDS-only (st dbuf): wait LDS, barrier — NO vmem drain
    asm volatile("s_waitcnt lgkmcnt(0)" ::: "memory");
    __builtin_amdgcn_s_barrier();
    asm volatile("" ::: "memory");
    up0 = un0; up1 = un1; up2 = un2; up3 = un3;
    un0 = uf0; un1 = uf1; un2 = uf2; un3 = uf3;
    cb ^= 1;
  }
}

extern "C" void kernel_launch(void* const* d_in, const int* in_sizes, int n_in,
                              void* d_out, int out_size, void* d_ws, size_t ws_size,
                              hipStream_t stream) {
  const float* x = (const float*)d_in[0];
  const float* A = (const float*)d_in[1];
  const float* B = (const float*)d_in[2];
  const float* C = (const float*)d_in[3];

  char* ws = (char*)d_ws;
  _Float16* U = (_Float16*)ws;                            // 33.5 MB (swizzled)
  _Float16* AhT = (_Float16*)(ws + 33554432);             // 128 KB
  _Float16* Ch = (_Float16*)(ws + 33554432 + 131072);     // 128 KB
  _Float16* Zph = (_Float16*)(ws + 33554432 + 262144);    // 1 KB zeros
  float* out = (float*)d_out;

  hipLaunchKernelGGL(k_gemm_u, dim3(512), dim3(256), 0, stream, x, A, B, C, U, AhT,
                     Ch, Zph);
  hipLaunchKernelGGL(k_scan, dim3(256), dim3(512), 0, stream, U, AhT, Ch, Zph, out);
}

// Round 10
// 178.030 us; speedup vs baseline: 1.4429x; 1.1878x over previous
//
#include <hip/hip_runtime.h>

#define BSZ 8
#define LSEQ 8192
#define DDIM 256
#define CHUNK 16
#define WARM 32
#define STEPS (CHUNK + WARM)   // 48
#define CPB 16                 // chains per block

typedef float f32x4 __attribute__((ext_vector_type(4)));
typedef _Float16 h8 __attribute__((ext_vector_type(8)));
typedef _Float16 h4 __attribute__((ext_vector_type(4)));
typedef _Float16 h2 __attribute__((ext_vector_type(2)));

// U layout (R4-proven): row-major rows, cols swizzled within each 64-block:
//   U[row*256 + g64*64 + l15*4 + ct] == logical U[row][g64*64 + ct*16 + l15]
//
// Cross-round lessons enforced:
//  - R4/R8: scan sweet spot = 8 waves x 32 cols, CHUNK=16, 1 block/CU. The R4
//    kernel (55.5us measured) is restored VERBATIM below.
//  - R4-R9: the allocator clamps ~100 VGPR; any operand stream needing >~8
//    register destinations serializes at memory latency. Fix: operands live
//    in LDS (ds_read needs no persistent registers), staged by coalesced
//    high-MLP reg-bounce. gemm_u inner loop is now 100% LDS-fed.

// ---------------- U = x @ B^T (+ folded matrix conversions) ----------------
// 1024 blocks x 64 rows, 256 threads (4 waves x 16 rows), 2 blocks/CU.
// Per col-block cbk: stage B-tile (64 cols x 256 k) fp32->fp16 into LDS,
// then inner loop reads af (x) and bf (B) from LDS only. First 256 blocks
// also emit AhT/Ch/Zph for the scan (stream order makes this safe).
__global__ __launch_bounds__(256) void k_gemm_u(
    const float* __restrict__ x, const float* __restrict__ A,
    const float* __restrict__ B, const float* __restrict__ C,
    _Float16* __restrict__ U, _Float16* __restrict__ AhT,
    _Float16* __restrict__ Ch, _Float16* __restrict__ Zph) {
  __shared__ __align__(16) _Float16 xh[64][264];  // x tile, 264 pitch (proven)
  __shared__ __align__(16) _Float16 bs[64][264];  // B^T tile for current cbk
  const int tid = threadIdx.x, wv = tid >> 6, lane = tid & 63;
  const int l15 = lane & 15, q = lane >> 4;

  if (blockIdx.x < 256) {  // side duty: operand conversions for the scan
    const int r = blockIdx.x;
    AhT[tid * 256 + r] = (_Float16)A[r * 256 + tid];   // AhT[n][k] = A[k][n]
    Ch[r * 256 + tid] = (_Float16)C[r * 256 + tid];    // Ch[n][k]  = C[n][k]
    if (r == 0) { Zph[tid] = (_Float16)0.f; Zph[tid + 256] = (_Float16)0.f; }
  }

  const size_t rowbase = (size_t)blockIdx.x * 64;
#pragma unroll 4
  for (int i = 0; i < 16; ++i) {  // 4096 float4 = 64 rows x 64 float4/row
    const int f4 = i * 256 + tid;
    const int row = f4 >> 6, c4 = f4 & 63;
    float4 v = *(const float4*)(x + (rowbase + row) * 256 + c4 * 4);
    h4 h;
    h[0] = (_Float16)v.x; h[1] = (_Float16)v.y; h[2] = (_Float16)v.z; h[3] = (_Float16)v.w;
    *(h4*)&xh[row][c4 * 4] = h;
  }

#pragma unroll 1
  for (int cbk = 0; cbk < 4; ++cbk) {
    __syncthreads();  // protect bs from previous iteration's readers
    // stage B^T tile: local row = output col n - cbk*64; Bt[k][n] = B[n][k]
#pragma unroll 4
    for (int i = 0; i < 16; ++i) {
      const int f4 = i * 256 + tid;
      const int row = f4 >> 6, c4 = f4 & 63;
      float4 v = *(const float4*)(B + (size_t)(cbk * 64 + row) * 256 + c4 * 4);
      h4 h;
      h[0] = (_Float16)v.x; h[1] = (_Float16)v.y; h[2] = (_Float16)v.z; h[3] = (_Float16)v.w;
      *(h4*)&bs[row][c4 * 4] = h;
    }
    __syncthreads();

    f32x4 acc[4] = {};  // this wave's 16 rows x (4 ct x 16) cols
#pragma unroll
    for (int kb = 0; kb < 8; ++kb) {
      h8 af = *(const h8*)&xh[wv * 16 + l15][kb * 32 + q * 8];
#pragma unroll
      for (int ct = 0; ct < 4; ++ct) {
        h8 bf = *(const h8*)&bs[ct * 16 + l15][kb * 32 + q * 8];
        acc[ct] = __builtin_amdgcn_mfma_f32_16x16x32_f16(af, bf, acc[ct], 0, 0, 0);
      }
    }
    const size_t grow = rowbase + wv * 16 + q * 4;
#pragma unroll
    for (int r = 0; r < 4; ++r) {
      h4 hv;
      hv[0] = (_Float16)acc[0][r]; hv[1] = (_Float16)acc[1][r];
      hv[2] = (_Float16)acc[2][r]; hv[3] = (_Float16)acc[3][r];
      *(h4*)(U + (grow + r) * 256 + cbk * 64 + l15 * 4) = hv;  // swizzled layout
    }
  }
}

// ---------------- fused MFMA scan + out-projection (R4 kernel, verbatim) ----
// 256 blocks / CHUNK=16 / 1 block/CU; 8 waves x 32 cols (64KB LDS af/step).
// Measured 55.5us in R4. No changes.
__global__ __launch_bounds__(512, 2) void k_scan(const _Float16* __restrict__ U,
                                                 const _Float16* __restrict__ AhT,
                                                 const _Float16* __restrict__ Ch,
                                                 const _Float16* __restrict__ Zp,
                                                 float* __restrict__ O) {
  __shared__ __align__(16) _Float16 st[2][CPB][264];  // state dbuf, proven layout
  const int tid = threadIdx.x, wv = tid >> 6, lane = tid & 63;
  const int l15 = lane & 15, q = lane >> 4;
  const int g64 = wv >> 1, hf = wv & 1;   // wave owns cols g64*64 + (2hf+ctl)*16 + l15
  const int b = blockIdx.x >> 5;
  const int c0 = (blockIdx.x & 31) * CPB;
  const size_t bbase = (size_t)b * LSEQ;

  h8 bf[2][8], cf[2][8];
#pragma unroll
  for (int ctl = 0; ctl < 2; ++ctl)
#pragma unroll
    for (int kb = 0; kb < 8; ++kb) {
      const size_t mo = (size_t)(g64 * 64 + (2 * hf + ctl) * 16 + l15) * 256 + kb * 32 + q * 8;
      bf[ctl][kb] = *(const h8*)(AhT + mo);
      cf[ctl][kb] = *(const h8*)(Ch + mo);
    }

  for (int i = tid; i < CPB * 264; i += 512) ((_Float16*)st[0])[i] = (_Float16)0.f;

  // per-lane U fragment load (2 ct-values, 4B) for chain q*4+r at local time t
  auto uload = [&](int t, int r) -> h2 {
    const int lr = (c0 + q * 4 + r) * CHUNK + t;
    const _Float16* p = (lr < 0 || lr >= LSEQ)
                            ? (Zp + l15 * 4 + 2 * hf)
                            : (U + (bbase + (size_t)lr) * 256 + g64 * 64 + l15 * 4 + 2 * hf);
    return *(const h2*)p;
  };

  // O running pointers: col base for ctl=0; ctl=1 is +16 floats
  float* op[4];
#pragma unroll
  for (int r = 0; r < 4; ++r)
    op[r] = O + (bbase + (size_t)(c0 + q * 4 + r) * CHUNK) * 256 + g64 * 64 + 2 * hf * 16 + l15;

  h2 up0 = uload(-WARM, 0), up1 = uload(-WARM, 1), up2 = uload(-WARM, 2), up3 = uload(-WARM, 3);
  __syncthreads();  // one full drain: zero-init + frag loads

  int cb = 0;
#pragma unroll 1
  for (int g = 0; g <= STEPS; ++g) {
    const int t = g - WARM;  // computes S_t (g<STEPS); emits O_{t-1} (t>=1)
    // prefetch next step's U fragments (overlaps this step's MFMA; never drained)
    h2 un0 = uload(t + 1, 0), un1 = uload(t + 1, 1), un2 = uload(t + 1, 2), un3 = uload(t + 1, 3);
    if (g < STEPS) {
      f32x4 acc[2];
#pragma unroll
      for (int ctl = 0; ctl < 2; ++ctl) {
        acc[ctl][0] = (float)up0[ctl]; acc[ctl][1] = (float)up1[ctl];
        acc[ctl][2] = (float)up2[ctl]; acc[ctl][3] = (float)up3[ctl];
      }
      if (t >= 1) {
        f32x4 acc2[2] = {};
#pragma unroll
        for (int kb = 0; kb < 8; ++kb) {
          h8 af = *(const h8*)&st[cb][l15][kb * 32 + q * 8];
#pragma unroll
          for (int ctl = 0; ctl < 2; ++ctl)
            acc[ctl] = __builtin_amdgcn_mfma_f32_16x16x32_f16(af, bf[ctl][kb], acc[ctl], 0, 0, 0);
#pragma unroll
          for (int ctl = 0; ctl < 2; ++ctl)
            acc2[ctl] = __builtin_amdgcn_mfma_f32_16x16x32_f16(af, cf[ctl][kb], acc2[ctl], 0, 0, 0);
        }
#pragma unroll
        for (int ctl = 0; ctl < 2; ++ctl)
#pragma unroll
          for (int r = 0; r < 4; ++r)
            st[cb ^ 1][q * 4 + r][g64 * 64 + (2 * hf + ctl) * 16 + l15] = (_Float16)acc[ctl][r];
#pragma unroll
        for (int r = 0; r < 4; ++r) {
          op[r][0] = acc2[0][r];
          op[r][16] = acc2[1][r];
          op[r] += 256;
        }
      } else {
#pragma unroll
        for (int kb = 0; kb < 8; ++kb) {
          h8 af = *(const h8*)&st[cb][l15][kb * 32 + q * 8];
#pragma unroll
          for (int ctl = 0; ctl < 2; ++ctl)
            acc[ctl] = __builtin_amdgcn_mfma_f32_16x16x32_f16(af, bf[ctl][kb], acc[ctl], 0, 0, 0);
        }
#pragma unroll
        for (int ctl = 0; ctl < 2; ++ctl)
#pragma unroll
          for (int r = 0; r < 4; ++r)
            st[cb ^ 1][q * 4 + r][g64 * 64 + (2 * hf + ctl) * 16 + l15] = (_Float16)acc[ctl][r];
      }
    } else {  // g == STEPS: final O_{CHUNK-1} only
      f32x4 acc2[2] = {};
#pragma unroll
      for (int kb = 0; kb < 8; ++kb) {
        h8 af = *(const h8*)&st[cb][l15][kb * 32 + q * 8];
#pragma unroll
        for (int ctl = 0; ctl < 2; ++ctl)
          acc2[ctl] = __builtin_amdgcn_mfma_f32_16x16x32_f16(af, cf[ctl][kb], acc2[ctl], 0, 0, 0);
      }
#pragma unroll
      for (int r = 0; r < 4; ++r) {
        op[r][0] = acc2[0][r];
        op[r][16] = acc2[1][r];
      }
    }
    // cross-wave hazard is LDS-only (st dbuf): wait LDS, barrier — NO vmem drain
    asm volatile("s_waitcnt lgkmcnt(0)" ::: "memory");
    __builtin_amdgcn_s_barrier();
    asm volatile("" ::: "memory");
    up0 = un0; up1 = un1; up2 = un2; up3 = un3;
    cb ^= 1;
  }
}

extern "C" void kernel_launch(void* const* d_in, const int* in_sizes, int n_in,
                              void* d_out, int out_size, void* d_ws, size_t ws_size,
                              hipStream_t stream) {
  const float* x = (const float*)d_in[0];
  const float* A = (const float*)d_in[1];
  const float* B = (const float*)d_in[2];
  const float* C = (const float*)d_in[3];

  char* ws = (char*)d_ws;
  _Float16* U = (_Float16*)ws;                            // 33.5 MB (swizzled)
  _Float16* AhT = (_Float16*)(ws + 33554432);             // 128 KB
  _Float16* Ch = (_Float16*)(ws + 33554432 + 131072);     // 128 KB
  _Float16* Zph = (_Float16*)(ws + 33554432 + 262144);    // 1 KB zeros
  float* out = (float*)d_out;

  hipLaunchKernelGGL(k_gemm_u, dim3(1024), dim3(256), 0, stream, x, A, B, C, U, AhT,
                     Ch, Zph);
  hipLaunchKernelGGL(k_scan, dim3(256), dim3(512), 0, stream, U, AhT, Ch, Zph, out);
}